// Round 6
// baseline (211.879 us; speedup 1.0000x reference)
//
#include <hip/hip_runtime.h>
#include <cstdint>
#include <cstddef>

// Problem constants (fixed by the reference)
#define B_DIM 8192
#define C_DIM 4096
#define F_DIM 1024
#define O_DIM 10
#define NSLICE 32  // C_DIM / 128 partial slices

typedef __attribute__((ext_vector_type(8))) __bf16 bf16x8;
typedef __attribute__((ext_vector_type(8))) unsigned short ushort8;
typedef __attribute__((ext_vector_type(4))) float f32x4;

// ---------------------------------------------------------------------------
// fp32 -> bf16 round-to-nearest-even
__device__ __forceinline__ unsigned short f2bf(float f) {
  unsigned int u = __builtin_bit_cast(unsigned int, f);
  u += 0x7fffu + ((u >> 16) & 1u);
  return (unsigned short)(u >> 16);
}

// ---------------------------------------------------------------------------
// Wave-per-row prep: rows [0,B_DIM) = x, rows [B_DIM, B_DIM+C_DIM) = loc.
// Converts fp32 row -> bf16 and computes fp32 ||row||^2. No LDS, no barrier.
__global__ __launch_bounds__(512) void prep_merged(
    const float* __restrict__ x, const float* __restrict__ loc,
    unsigned short* __restrict__ xb, unsigned short* __restrict__ locb,
    float* __restrict__ x2, float* __restrict__ c2) {
  const int wave = threadIdx.x >> 6;
  const int lane = threadIdx.x & 63;
  const int row = blockIdx.x * 8 + wave;
  const float* src;
  unsigned short* dst;
  float* nrm;
  if (row < B_DIM) {
    src = x + (size_t)row * F_DIM;
    dst = xb + (size_t)row * F_DIM;
    nrm = x2 + row;
  } else {
    const int r = row - B_DIM;
    src = loc + (size_t)r * F_DIM;
    dst = locb + (size_t)r * F_DIM;
    nrm = c2 + r;
  }
  float ss = 0.f;
#pragma unroll
  for (int i = 0; i < 4; ++i) {
    const float4 v = reinterpret_cast<const float4*>(src)[lane + 64 * i];
    ss += v.x * v.x + v.y * v.y + v.z * v.z + v.w * v.w;
    ushort4 o;
    o.x = f2bf(v.x); o.y = f2bf(v.y); o.z = f2bf(v.z); o.w = f2bf(v.w);
    reinterpret_cast<ushort4*>(dst)[lane + 64 * i] = o;
  }
#pragma unroll
  for (int m = 1; m <= 32; m <<= 1) ss += __shfl_xor(ss, m, 64);
  if (lane == 0) *nrm = ss;
}

// ---------------------------------------------------------------------------
// Fused: S = loc_bf16 @ x_bf16^T (MFMA), phi = exp(-sqrt(max(c2+x2-2S,0))/scale),
// P[slice][b][o] = sum_{c in 128-slice} phi[c][b] * w[o][c]   (no atomics).
//
// Tile: 128 c (M) x 256 b (N), BK=32; 512 threads = 8 waves in (c-half 2) x
// (b-quarter 4); each wave 64x64 via 4x4 grid of 16x16x32 MFMAs.
// acc[4][4] = 64 VGPR/lane -> total <=128 (__launch_bounds__(512,4)) ->
// 4 waves/SIMD, and with 72 KB LDS/block -> 2 blocks/CU co-resident (the
// m114 cross-block overlap fills barrier stalls that R5's 1-block/CU
// lockstep could not).
//
// K-loop pipeline: 3 LDS buffers, prefetch depth 2, ONE barrier per iter:
//   s_waitcnt vmcnt(3); s_barrier; ISSUE(buf i+2); compute(buf i)
//
// XCD swizzle: blockIdx&7 = XCD; each XCD owns a 4-cIdx loc stripe (1 MB,
// L2-resident => A staging is pure L2 hits); 4 co-resident blocks share each
// x-tile.
__global__ __launch_bounds__(512, 4) void rbf_fused(
    const unsigned short* __restrict__ locb,  // [C_DIM][F_DIM] bf16 bits
    const unsigned short* __restrict__ xb,    // [B_DIM][F_DIM] bf16 bits
    const float* __restrict__ c2,             // [C_DIM]
    const float* __restrict__ x2,             // [B_DIM]
    const float* __restrict__ scale,          // [C_DIM]
    const float* __restrict__ w,              // [O_DIM][C_DIM]
    float* __restrict__ P) {                  // [NSLICE][B_DIM][O_DIM]
  extern __shared__ unsigned short smem[];
  unsigned short* As = smem;             // 3 x 128x32 = 24 KB
  unsigned short* Bs = smem + 3 * 4096;  // 3 x 256x32 = 48 KB

  const int tid = threadIdx.x;
  const int wave = tid >> 6;
  const int lane = tid & 63;
  const int quad = lane >> 4;
  const int n15 = lane & 15;

  // XCD-aware mapping: g = XCD; cIdx stripe {4g..4g+3} fastest, then bIdx.
  const int id = blockIdx.x;
  const int g = id & 7;
  const int j = id >> 3;
  const int cIdx = (g << 2) + (j & 3);  // 0..31
  const int bIdx = j >> 2;              // 0..31
  const int cBase = cIdx << 7;
  const int bBase = bIdx << 8;

  const int wch = wave >> 2;  // c-half 0/1
  const int bq = wave & 3;    // b-quarter 0..3
  const int wcc = wch * 64;   // wave centroid offset in tile
  const int wbb = bq * 64;    // wave batch offset in tile

  float x2v[4];
#pragma unroll
  for (int tj = 0; tj < 4; ++tj) x2v[tj] = x2[bBase + wbb + tj * 16 + n15];

  // Staging: A tile 128x32 (8 KB) = 8 chunks of 1 KB; wave handles chunk
  // [wave] (rows 16w..16w+15), 1 load. B tile 256x32 (16 KB) = 16 chunks;
  // wave handles chunks {2w, 2w+1} (rows 32w..32w+31), 2 loads. Within a
  // chunk (16 rows x 64 B): lane l -> row l>>2, physical 16-B slot l&3,
  // global k-chunk (l&3)^((l>>3)&3) (XOR swizzle; reader matches).
  const int rowIn = lane >> 2;
  const int colOff = ((lane & 3) ^ ((lane >> 3) & 3)) * 8;  // bf16 elems

  const unsigned short* aS0 = locb + (size_t)(cBase + wave * 16 + rowIn) * F_DIM + colOff;
  const unsigned short* bS0 = xb + (size_t)(bBase + wave * 32 + 0 + rowIn) * F_DIM + colOff;
  const unsigned short* bS1 = xb + (size_t)(bBase + wave * 32 + 16 + rowIn) * F_DIM + colOff;

#define ISSUE(p, k0)                                                                     \
  do {                                                                                   \
    __builtin_amdgcn_global_load_lds(                                                    \
        (const __attribute__((address_space(1))) void*)(aS0 + (k0)),                     \
        (__attribute__((address_space(3))) void*)&As[(p) * 4096 + wave * 512],           \
        16, 0, 0);                                                                       \
    __builtin_amdgcn_global_load_lds(                                                    \
        (const __attribute__((address_space(1))) void*)(bS0 + (k0)),                     \
        (__attribute__((address_space(3))) void*)&Bs[(p) * 8192 + (wave * 2 + 0) * 512], \
        16, 0, 0);                                                                       \
    __builtin_amdgcn_global_load_lds(                                                    \
        (const __attribute__((address_space(1))) void*)(bS1 + (k0)),                     \
        (__attribute__((address_space(3))) void*)&Bs[(p) * 8192 + (wave * 2 + 1) * 512], \
        16, 0, 0);                                                                       \
  } while (0)

  f32x4 acc[4][4];
  const f32x4 zero = {0.f, 0.f, 0.f, 0.f};
#pragma unroll
  for (int i = 0; i < 4; ++i)
#pragma unroll
    for (int jj = 0; jj < 4; ++jj) acc[i][jj] = zero;

  const int swA = (quad ^ ((n15 >> 1) & 3)) * 8;

  auto compute = [&](int p) {
    const unsigned short* Ab = &As[p * 4096];
    const unsigned short* Bb = &Bs[p * 8192];
    bf16x8 af[4], bfr[4];
#pragma unroll
    for (int ti = 0; ti < 4; ++ti)
      af[ti] = __builtin_bit_cast(
          bf16x8, *(const ushort8*)&Ab[(wcc + ti * 16 + n15) * 32 + swA]);
#pragma unroll
    for (int tj = 0; tj < 4; ++tj)
      bfr[tj] = __builtin_bit_cast(
          bf16x8, *(const ushort8*)&Bb[(wbb + tj * 16 + n15) * 32 + swA]);
#pragma unroll
    for (int ti = 0; ti < 4; ++ti)
#pragma unroll
      for (int tj = 0; tj < 4; ++tj)
        acc[ti][tj] = __builtin_amdgcn_mfma_f32_16x16x32_bf16(
            af[ti], bfr[tj], acc[ti][tj], 0, 0, 0);
  };

  // Quiesce vm counter so in-loop vmcnt(N) semantics are exact.
  asm volatile("s_waitcnt vmcnt(0)" ::: "memory");
  ISSUE(0, 0);
  ISSUE(1, 32);
#pragma unroll
  for (int it = 0; it < 32; ++it) {
    if (it == 31) {
      asm volatile("s_waitcnt vmcnt(0)\ns_barrier" ::: "memory");
    } else {
      asm volatile("s_waitcnt vmcnt(3)\ns_barrier" ::: "memory");
    }
    if (it < 30) ISSUE((it + 2) % 3, (it + 2) * 32);
    compute(it % 3);
  }
  __syncthreads();  // all waves done reading LDS before epilogue reuse

  // ---- epilogue ----
  // acc[ti][tj][r]: c_local = wcc+ti*16+quad*4+r, b_local = wbb+tj*16+n15.
  // Stage w / c2 / (-1/scale) into the dead As region (24 KB avail).
  float* wlds = reinterpret_cast<float*>(As);  // [O_DIM*128] = 5 KB
  float* c2l = wlds + O_DIM * 128;             // [128]
  float* nisl = c2l + 128;                     // [128]
  for (int i = tid; i < O_DIM * 128; i += 512)
    wlds[i] = w[(i >> 7) * C_DIM + cBase + (i & 127)];
  if (tid < 128) {
    c2l[tid] = c2[cBase + tid];
    nisl[tid] = -1.0f / scale[cBase + tid];
  }
  __syncthreads();

  float partial[4][O_DIM];
#pragma unroll
  for (int tj = 0; tj < 4; ++tj)
#pragma unroll
    for (int o = 0; o < O_DIM; ++o) partial[tj][o] = 0.f;

#pragma unroll
  for (int ti = 0; ti < 4; ++ti) {
    const int clq = wcc + ti * 16 + quad * 4;
    const f32x4 c24 = *(const f32x4*)&c2l[clq];
    const f32x4 ns4 = *(const f32x4*)&nisl[clq];
    float phi[4][4];  // [tj][r]
#pragma unroll
    for (int tj = 0; tj < 4; ++tj)
#pragma unroll
      for (int r = 0; r < 4; ++r) {
        const float s = acc[ti][tj][r];
        const float sq = fmaxf(x2v[tj] + c24[r] - 2.0f * s, 0.0f);
        phi[tj][r] = __expf(sqrtf(sq) * ns4[r]);
      }
#pragma unroll
    for (int o = 0; o < O_DIM; ++o) {
      const f32x4 w4 = *(const f32x4*)&wlds[o * 128 + clq];
#pragma unroll
      for (int tj = 0; tj < 4; ++tj)
#pragma unroll
        for (int r = 0; r < 4; ++r)
          partial[tj][o] = fmaf(phi[tj][r], w4[r], partial[tj][o]);
    }
  }

  // reduce over the 4 quads (lanes ^16, ^32 share the same batch index)
#pragma unroll
  for (int tj = 0; tj < 4; ++tj)
#pragma unroll
    for (int o = 0; o < O_DIM; ++o) {
      float v = partial[tj][o];
      v += __shfl_xor(v, 16, 64);
      v += __shfl_xor(v, 32, 64);
      partial[tj][o] = v;
    }

  // Cross-wave (c-halves) reduce via LDS (alias dead Bs), then store.
  float* red = reinterpret_cast<float*>(Bs);  // 2560 floats, region is dead
  if (wch == 0 && quad == 0) {
#pragma unroll
    for (int tj = 0; tj < 4; ++tj)
#pragma unroll
      for (int o = 0; o < O_DIM; ++o)
        red[(wbb + tj * 16 + n15) * O_DIM + o] = partial[tj][o];
  }
  __syncthreads();
  if (wch == 1 && quad == 0) {
#pragma unroll
    for (int tj = 0; tj < 4; ++tj)
#pragma unroll
      for (int o = 0; o < O_DIM; ++o)
        red[(wbb + tj * 16 + n15) * O_DIM + o] += partial[tj][o];
  }
  __syncthreads();
  float* Pdst = P + (size_t)cIdx * (B_DIM * O_DIM) + (size_t)bBase * O_DIM;
  for (int i = tid; i < 256 * O_DIM; i += 512) Pdst[i] = red[i];
}

// ---------------------------------------------------------------------------
// out[b][o] = sum_k P[k][b][o]
__global__ __launch_bounds__(256) void reduce_partials(const float* __restrict__ P,
                                                       float* __restrict__ out) {
  const int i = blockIdx.x * 256 + threadIdx.x;  // 0 .. B_DIM*O_DIM-1
  float s = 0.f;
#pragma unroll
  for (int k = 0; k < NSLICE; ++k) s += P[(size_t)k * (B_DIM * O_DIM) + i];
  out[i] = s;
}

// ---------------------------------------------------------------------------
extern "C" void kernel_launch(void* const* d_in, const int* in_sizes, int n_in,
                              void* d_out, int out_size, void* d_ws, size_t ws_size,
                              hipStream_t stream) {
  const float* x = (const float*)d_in[0];      // [8192,1024]
  const float* loc = (const float*)d_in[1];    // [4096,1024]
  const float* scale = (const float*)d_in[2];  // [4096]
  const float* w = (const float*)d_in[3];      // [10,4096]
  float* out = (float*)d_out;                  // [8192,10]

  // workspace layout (~35.5 MB)
  char* ws = (char*)d_ws;
  unsigned short* xb = (unsigned short*)(ws);                              // 16 MB
  unsigned short* locb = (unsigned short*)(ws + (size_t)16 * 1024 * 1024); // 8 MB
  float* x2 = (float*)(ws + (size_t)24 * 1024 * 1024);                    // 32 KB
  float* c2 = (float*)(ws + (size_t)24 * 1024 * 1024 + 64 * 1024);        // 16 KB
  float* P = (float*)(ws + (size_t)25 * 1024 * 1024);                     // 10.5 MB

  // 72 KB dynamic LDS (static cap is 64 KB). Host-side attribute set;
  // idempotent, not a stream op — safe under graph capture.
  hipFuncSetAttribute((const void*)rbf_fused,
                      hipFuncAttributeMaxDynamicSharedMemorySize, 73728);

  prep_merged<<<(B_DIM + C_DIM) / 8, 512, 0, stream>>>(x, loc, xb, locb, x2, c2);

  rbf_fused<<<NSLICE * 32, 512, 73728, stream>>>(locb, xb, c2, x2, scale, w, P);

  reduce_partials<<<(B_DIM * O_DIM) / 256, 256, 0, stream>>>(P, out);
}

// Round 7
// 182.745 us; speedup vs baseline: 1.1594x; 1.1594x over previous
//
#include <hip/hip_runtime.h>
#include <cstdint>
#include <cstddef>

// Problem constants (fixed by the reference)
#define B_DIM 8192
#define C_DIM 4096
#define F_DIM 1024
#define O_DIM 10
#define NSLICE 16  // C_DIM / 256 partial slices

typedef __attribute__((ext_vector_type(8))) __bf16 bf16x8;
typedef __attribute__((ext_vector_type(8))) unsigned short ushort8;
typedef __attribute__((ext_vector_type(4))) float f32x4;

// ---------------------------------------------------------------------------
// fp32 -> bf16 round-to-nearest-even
__device__ __forceinline__ unsigned short f2bf(float f) {
  unsigned int u = __builtin_bit_cast(unsigned int, f);
  u += 0x7fffu + ((u >> 16) & 1u);
  return (unsigned short)(u >> 16);
}

// ---------------------------------------------------------------------------
// Wave-per-row prep: rows [0,B_DIM) = x, rows [B_DIM, B_DIM+C_DIM) = loc.
// Converts fp32 row -> bf16 and computes fp32 ||row||^2. No LDS, no barrier.
__global__ __launch_bounds__(512) void prep_merged(
    const float* __restrict__ x, const float* __restrict__ loc,
    unsigned short* __restrict__ xb, unsigned short* __restrict__ locb,
    float* __restrict__ x2, float* __restrict__ c2) {
  const int wave = threadIdx.x >> 6;
  const int lane = threadIdx.x & 63;
  const int row = blockIdx.x * 8 + wave;
  const float* src;
  unsigned short* dst;
  float* nrm;
  if (row < B_DIM) {
    src = x + (size_t)row * F_DIM;
    dst = xb + (size_t)row * F_DIM;
    nrm = x2 + row;
  } else {
    const int r = row - B_DIM;
    src = loc + (size_t)r * F_DIM;
    dst = locb + (size_t)r * F_DIM;
    nrm = c2 + r;
  }
  float ss = 0.f;
#pragma unroll
  for (int i = 0; i < 4; ++i) {
    const float4 v = reinterpret_cast<const float4*>(src)[lane + 64 * i];
    ss += v.x * v.x + v.y * v.y + v.z * v.z + v.w * v.w;
    ushort4 o;
    o.x = f2bf(v.x); o.y = f2bf(v.y); o.z = f2bf(v.z); o.w = f2bf(v.w);
    reinterpret_cast<ushort4*>(dst)[lane + 64 * i] = o;
  }
#pragma unroll
  for (int m = 1; m <= 32; m <<= 1) ss += __shfl_xor(ss, m, 64);
  if (lane == 0) *nrm = ss;
}

// ---------------------------------------------------------------------------
// Fused: S = loc_bf16 @ x_bf16^T (MFMA), phi = exp(-sqrt(max(c2+x2-2S,0))/scale),
// P[slice][b][o] = sum_{c in 256-slice} phi[c][b] * w[o][c]   (no atomics).
//
// Tile: 256 c (M) x 256 b (N), BK=64; 512 threads = 8 waves in (c-half 2) x
// (b-quarter 4); each wave 128x64 via 8x4 grid of 16x16x32 MFMAs x 2 k-substeps.
//
// K-loop: BK=64, 2 LDS buffers (128 KB dynamic, 1 blk/CU), 16 iterations ->
// HALF the barriers of the BK=32 version. Per iter:
//   s_waitcnt vmcnt(0); s_barrier; ISSUE(next buf); compute(cur buf)
// The vmcnt(0) is hidden: loads were issued one full compute (~2.5k cyc) ago,
// >> the ~900-cyc HBM latency. wait-BEFORE-barrier makes all waves' DMA
// writes visible to every wave after the barrier; ISSUE-after-barrier makes
// overwriting the buffer read at iter-1 safe.
//
// XCD swizzle: blockIdx&7 = XCD; c-neighbors (2g,2g+1) sharing a b-tile are
// adjacent ids -> co-resident on one XCD -> L2 captures the pair (R5's
// best-measured mapping: FETCH ~90 MB).
__global__ __launch_bounds__(512, 2) void rbf_fused(
    const unsigned short* __restrict__ locb,  // [C_DIM][F_DIM] bf16 bits
    const unsigned short* __restrict__ xb,    // [B_DIM][F_DIM] bf16 bits
    const float* __restrict__ c2,             // [C_DIM]
    const float* __restrict__ x2,             // [B_DIM]
    const float* __restrict__ scale,          // [C_DIM]
    const float* __restrict__ w,              // [O_DIM][C_DIM]
    float* __restrict__ P) {                  // [NSLICE][B_DIM][O_DIM]
  extern __shared__ unsigned short smem[];
  unsigned short* As = smem;              // 2 x 256x64 = 64 KB
  unsigned short* Bs = smem + 2 * 16384;  // 2 x 256x64 = 64 KB

  const int tid = threadIdx.x;
  const int wave = tid >> 6;
  const int lane = tid & 63;
  const int quad = lane >> 4;
  const int n15 = lane & 15;

  // XCD-aware mapping: g = XCD, cIdx in {2g, 2g+1} fastest, then bIdx.
  const int id = blockIdx.x;
  const int g = id & 7;
  const int j = id >> 3;
  const int cIdx = (g << 1) + (j & 1);  // 0..15
  const int bIdx = j >> 1;              // 0..31
  const int cBase = cIdx << 8;
  const int bBase = bIdx << 8;

  const int wch = wave >> 2;  // c-half 0/1
  const int bq = wave & 3;    // b-quarter 0..3
  const int wcc = wch * 128;  // wave centroid offset in tile
  const int wbb = bq * 64;    // wave batch offset in tile

  float x2v[4];
#pragma unroll
  for (int tj = 0; tj < 4; ++tj) x2v[tj] = x2[bBase + wbb + tj * 16 + n15];

  // Staging: each buffer tile is 256 rows x 64 k (32 KB) = 32 chunks of 1 KB
  // (8 rows x 128 B). Wave handles 4 A-chunks + 4 B-chunks (rows 32w..32w+31).
  // Within a chunk: lane l -> row l>>3, physical 16-B slot l&7; global
  // k-chunk q = (l&7)^((l>>3)&7)  (XOR swizzle over 8 slots; reader matches,
  // giving full 32-bank spread for ds_read_b128).
  const int rowIn = lane >> 3;                              // 0..7
  const int colOff = ((lane & 7) ^ ((lane >> 3) & 7)) * 8;  // bf16 elems

  const unsigned short* aS[4];
  const unsigned short* bS[4];
#pragma unroll
  for (int c = 0; c < 4; ++c) {
    aS[c] = locb + (size_t)(cBase + wave * 32 + c * 8 + rowIn) * F_DIM + colOff;
    bS[c] = xb + (size_t)(bBase + wave * 32 + c * 8 + rowIn) * F_DIM + colOff;
  }

#define ISSUE(p, k0)                                                                       \
  do {                                                                                     \
    _Pragma("unroll") for (int c = 0; c < 4; ++c) {                                        \
      __builtin_amdgcn_global_load_lds(                                                    \
          (const __attribute__((address_space(1))) void*)(aS[c] + (k0)),                   \
          (__attribute__((address_space(3))) void*)&As[(p) * 16384 + (wave * 4 + c) * 512],\
          16, 0, 0);                                                                       \
      __builtin_amdgcn_global_load_lds(                                                    \
          (const __attribute__((address_space(1))) void*)(bS[c] + (k0)),                   \
          (__attribute__((address_space(3))) void*)&Bs[(p) * 16384 + (wave * 4 + c) * 512],\
          16, 0, 0);                                                                       \
    }                                                                                      \
  } while (0)

  f32x4 acc[8][4];
  const f32x4 zero = {0.f, 0.f, 0.f, 0.f};
#pragma unroll
  for (int i = 0; i < 8; ++i)
#pragma unroll
    for (int jj = 0; jj < 4; ++jj) acc[i][jj] = zero;

  const int n7 = n15 & 7;

  auto compute = [&](int p) {
    const unsigned short* Ab = &As[p * 16384];
    const unsigned short* Bb = &Bs[p * 16384];
#pragma unroll
    for (int sig = 0; sig < 2; ++sig) {
      const int slot = ((sig * 4 + quad) ^ n7) * 8;  // swizzled 16-B slot
      bf16x8 af[8], bfr[4];
#pragma unroll
      for (int ti = 0; ti < 8; ++ti)
        af[ti] = __builtin_bit_cast(
            bf16x8, *(const ushort8*)&Ab[(wcc + ti * 16 + n15) * 64 + slot]);
#pragma unroll
      for (int tj = 0; tj < 4; ++tj)
        bfr[tj] = __builtin_bit_cast(
            bf16x8, *(const ushort8*)&Bb[(wbb + tj * 16 + n15) * 64 + slot]);
#pragma unroll
      for (int ti = 0; ti < 8; ++ti)
#pragma unroll
        for (int tj = 0; tj < 4; ++tj)
          acc[ti][tj] = __builtin_amdgcn_mfma_f32_16x16x32_bf16(
              af[ti], bfr[tj], acc[ti][tj], 0, 0, 0);
    }
  };

  // Prologue: quiesce, stage buffer 0.
  asm volatile("s_waitcnt vmcnt(0)" ::: "memory");
  ISSUE(0, 0);
#pragma unroll
  for (int it = 0; it < 16; ++it) {
    // All my buf-it loads landed, then barrier => ALL waves' loads landed.
    asm volatile("s_waitcnt vmcnt(0)\ns_barrier" ::: "memory");
    if (it < 15) ISSUE((it + 1) & 1, (it + 1) * 64);  // safe: buf read at it-1
    compute(it & 1);
  }
  __syncthreads();  // all waves done reading LDS before epilogue reuse

  // ---- epilogue ----
  // acc[ti][tj][r]: c_local = wcc+ti*16+quad*4+r, b_local = wbb+tj*16+n15.
  // Stage w / c2 / (-1/scale) into the dead As region (64 KB avail).
  float* wlds = reinterpret_cast<float*>(As);  // [O_DIM*256] = 10 KB
  float* c2l = wlds + O_DIM * 256;             // [256]
  float* nisl = c2l + 256;                     // [256]
  for (int i = tid; i < O_DIM * 256; i += 512)
    wlds[i] = w[(i >> 8) * C_DIM + cBase + (i & 255)];
  if (tid < 256) {
    c2l[tid] = c2[cBase + tid];
    nisl[tid] = -1.0f / scale[cBase + tid];
  }
  __syncthreads();

  float partial[4][O_DIM];
#pragma unroll
  for (int tj = 0; tj < 4; ++tj)
#pragma unroll
    for (int o = 0; o < O_DIM; ++o) partial[tj][o] = 0.f;

#pragma unroll
  for (int ti = 0; ti < 8; ++ti) {
    const int clq = wcc + ti * 16 + quad * 4;
    const f32x4 c24 = *(const f32x4*)&c2l[clq];
    const f32x4 ns4 = *(const f32x4*)&nisl[clq];
    float phi[4][4];  // [tj][r]
#pragma unroll
    for (int tj = 0; tj < 4; ++tj)
#pragma unroll
      for (int r = 0; r < 4; ++r) {
        const float s = acc[ti][tj][r];
        const float sq = fmaxf(x2v[tj] + c24[r] - 2.0f * s, 0.0f);
        phi[tj][r] = __expf(sqrtf(sq) * ns4[r]);
      }
#pragma unroll
    for (int o = 0; o < O_DIM; ++o) {
      const f32x4 w4 = *(const f32x4*)&wlds[o * 256 + clq];
#pragma unroll
      for (int tj = 0; tj < 4; ++tj)
#pragma unroll
        for (int r = 0; r < 4; ++r)
          partial[tj][o] = fmaf(phi[tj][r], w4[r], partial[tj][o]);
    }
  }

  // reduce over the 4 quads (lanes ^16, ^32 share the same batch index)
#pragma unroll
  for (int tj = 0; tj < 4; ++tj)
#pragma unroll
    for (int o = 0; o < O_DIM; ++o) {
      float v = partial[tj][o];
      v += __shfl_xor(v, 16, 64);
      v += __shfl_xor(v, 32, 64);
      partial[tj][o] = v;
    }

  // Cross-wave (c-halves) reduce via LDS (alias dead Bs), then store.
  float* red = reinterpret_cast<float*>(Bs);  // 2560 floats, region is dead
  if (wch == 0 && quad == 0) {
#pragma unroll
    for (int tj = 0; tj < 4; ++tj)
#pragma unroll
      for (int o = 0; o < O_DIM; ++o)
        red[(wbb + tj * 16 + n15) * O_DIM + o] = partial[tj][o];
  }
  __syncthreads();
  if (wch == 1 && quad == 0) {
#pragma unroll
    for (int tj = 0; tj < 4; ++tj)
#pragma unroll
      for (int o = 0; o < O_DIM; ++o)
        red[(wbb + tj * 16 + n15) * O_DIM + o] += partial[tj][o];
  }
  __syncthreads();
  float* Pdst = P + (size_t)cIdx * (B_DIM * O_DIM) + (size_t)bBase * O_DIM;
  for (int i = tid; i < 256 * O_DIM; i += 512) Pdst[i] = red[i];
}

// ---------------------------------------------------------------------------
// out[b][o] = sum_k P[k][b][o]
__global__ __launch_bounds__(256) void reduce_partials(const float* __restrict__ P,
                                                       float* __restrict__ out) {
  const int i = blockIdx.x * 256 + threadIdx.x;  // 0 .. B_DIM*O_DIM-1
  float s = 0.f;
#pragma unroll
  for (int k = 0; k < NSLICE; ++k) s += P[(size_t)k * (B_DIM * O_DIM) + i];
  out[i] = s;
}

// ---------------------------------------------------------------------------
extern "C" void kernel_launch(void* const* d_in, const int* in_sizes, int n_in,
                              void* d_out, int out_size, void* d_ws, size_t ws_size,
                              hipStream_t stream) {
  const float* x = (const float*)d_in[0];      // [8192,1024]
  const float* loc = (const float*)d_in[1];    // [4096,1024]
  const float* scale = (const float*)d_in[2];  // [4096]
  const float* w = (const float*)d_in[3];      // [10,4096]
  float* out = (float*)d_out;                  // [8192,10]

  // workspace layout (~30.3 MB)
  char* ws = (char*)d_ws;
  unsigned short* xb = (unsigned short*)(ws);                              // 16 MB
  unsigned short* locb = (unsigned short*)(ws + (size_t)16 * 1024 * 1024); // 8 MB
  float* x2 = (float*)(ws + (size_t)24 * 1024 * 1024);                    // 32 KB
  float* c2 = (float*)(ws + (size_t)24 * 1024 * 1024 + 64 * 1024);        // 16 KB
  float* P = (float*)(ws + (size_t)25 * 1024 * 1024);                     // 5.24 MB

  // 128 KB dynamic LDS (static cap is 64 KB). Host-side attribute set;
  // idempotent, not a stream op — safe under graph capture.
  hipFuncSetAttribute((const void*)rbf_fused,
                      hipFuncAttributeMaxDynamicSharedMemorySize, 131072);

  prep_merged<<<(B_DIM + C_DIM) / 8, 512, 0, stream>>>(x, loc, xb, locb, x2, c2);

  rbf_fused<<<NSLICE * 32, 512, 131072, stream>>>(locb, xb, c2, x2, scale, w, P);

  reduce_partials<<<(B_DIM * O_DIM) / 256, 256, 0, stream>>>(P, out);
}